// Round 1
// baseline (403.012 us; speedup 1.0000x reference)
//
#include <hip/hip_runtime.h>
#include <math.h>

// LeCun LCN, fused single kernel, radius-5 truncated Gaussian (taps d>=6 have
// total weight 1.2e-8 -- numerically invisible vs the 4.9e-2 threshold).
//
// mean     = gauss11x11 * x          (separable, zero-pad SAME)
// centered = x - mean
// var      = gauss11x11 * centered^2 (zero-pad SAME)
// out      = centered / (sqrt(var) + 1e-4) * mask
//
// Tile 32x16 (96 flat cols), 256 threads, LDS 32.0 KB -> 5 blocks/CU
// (was 32x32 / 48.1 KB / 3 blocks/CU: occupancy capped at 37.5%, measured 23%,
//  latency-bound with VALUBusy 32% and HBM 10%).
// Strides padded to break bank conflicts (SQ_LDS_BANK_CONFLICT was 2.0e7):
//   S1W=132 (33 quads, odd -> rows rotate banks; P1 stores hit all 8 quads)
//   HCW=100 (25 quads, odd -> P3 stores / P4 11-row reads de-alias; 96 floats
//            = 384 B was 0 mod 128 B: every row on the same banks)
//
//  P1: hblur(x)        -> s1[36][132]  rows h0-10..h0+25, flat cols fc0..fc0+125
//  P2: vblur(s1)=mean; centered -> b2[26][132]  rows h0-5..h0+20
//  P3: hblur(b2^2)     -> hc (reuse s1) [26][100]
//  P4: vblur(hc)=var; epilogue, float4 stores
// Vertical phases: thread-per-(row, float4-group), 11 aligned ds_read_b128,
// 4 independent accumulator chains per thread.

#define TW 32
#define TH 16
#define FC 96            // 3*TW
#define S1W 132          // LDS row stride (126 cols used + pad; 33 quads -> odd rotation)
#define S1R 36           // TH + 20
#define B2R 26           // TH + 10
#define HCW 100          // hc row stride (25 quads -> odd rotation)

__global__ __launch_bounds__(256, 5)
void lecun_lcn_kernel(const float* __restrict__ x,
                      const float* __restrict__ mask,
                      float* __restrict__ out)
{
    __shared__ float s1[S1R * S1W];   // 19,008 B
    __shared__ float b2[B2R * S1W];   // 13,728 B  (total 32,736 B -> 5 blocks/CU)

    const int tid = threadIdx.x;
    const int w0  = blockIdx.x * TW;
    const int h0  = blockIdx.y * TH;
    const int bi  = blockIdx.z;
    const int fc0 = 3 * w0 - 15;      // flat col of s1/b2 index 0

    // 1D Gaussian (std=1), taps 0..5, normalized by the full 19-tap sum.
    const float K[6] = {
        3.9894227826685783e-01f,
        2.4197072322439816e-01f,
        5.3990966224238430e-02f,
        4.4318483882270000e-03f,
        1.3383022504889000e-04f,
        1.4867195067806000e-06f
    };

    const float* xb = x + (size_t)bi * 512 * 1536;

    // ---------------- Phase 1: hblur(x) -> s1 -------------------------------
    // task -> (row r of 36, run of 8 cols; 16 runs cover 128 cols)
    for (int t = tid; t < S1R * 16; t += 256) {
        const int r   = t >> 4;
        const int run = t & 15;
        const int h   = h0 - 10 + r;
        float* dst = &s1[r * S1W + run * 8];
        if ((unsigned)h >= 512u) {
            float4 z = make_float4(0.f, 0.f, 0.f, 0.f);
            ((float4*)dst)[0] = z; ((float4*)dst)[1] = z;
            continue;
        }
        const float* xrow = xb + (size_t)h * 1536;
        const int gc0 = fc0 + run * 8;     // first output flat col
        const int a   = gc0 - 17;          // window start, (gc0-15)%4==2 -> a%4==0
        float w[40];                       // covers [gc0-15, gc0+22] at w[2..39]
        if (a >= 0 && a <= 1536 - 40) {
            const float4* p = (const float4*)(xrow + a);
            #pragma unroll
            for (int q = 0; q < 10; ++q) {
                float4 v = p[q];
                w[4*q+0] = v.x; w[4*q+1] = v.y; w[4*q+2] = v.z; w[4*q+3] = v.w;
            }
        } else {
            #pragma unroll
            for (int i = 0; i < 40; ++i) {
                int j = a + i;
                w[i] = ((unsigned)j < 1536u) ? xrow[j] : 0.0f;
            }
        }
        float v1[8];
        #pragma unroll
        for (int i = 0; i < 8; ++i) {
            const int ci = 17 + i;
            float acc = K[0] * w[ci];
            #pragma unroll
            for (int d = 1; d <= 5; ++d)
                acc = fmaf(K[d], w[ci - 3*d] + w[ci + 3*d], acc);
            v1[i] = acc;
        }
        ((float4*)dst)[0] = make_float4(v1[0], v1[1], v1[2], v1[3]);
        ((float4*)dst)[1] = make_float4(v1[4], v1[5], v1[6], v1[7]);
    }
    __syncthreads();

    // ------- Phase 2: vblur(s1)=mean; centered = x - mean -> b2 -------------
    // task -> (row r of 26, float4-group g4 of 32)
    for (int t = tid; t < B2R * 32; t += 256) {
        const int r  = t >> 5;
        const int c4 = (t & 31) * 4;
        const int h  = h0 - 5 + r;
        float4* dst = (float4*)&b2[r * S1W + c4];
        if ((unsigned)h >= 512u) {
            *dst = make_float4(0.f, 0.f, 0.f, 0.f);
            continue;
        }
        float4 v = *(const float4*)&s1[(r + 5) * S1W + c4];
        float m0 = K[0] * v.x, m1 = K[0] * v.y, m2 = K[0] * v.z, m3 = K[0] * v.w;
        #pragma unroll
        for (int d = 1; d <= 5; ++d) {
            float4 aa = *(const float4*)&s1[(r + 5 - d) * S1W + c4];
            float4 bb = *(const float4*)&s1[(r + 5 + d) * S1W + c4];
            m0 = fmaf(K[d], aa.x + bb.x, m0);
            m1 = fmaf(K[d], aa.y + bb.y, m1);
            m2 = fmaf(K[d], aa.z + bb.z, m2);
            m3 = fmaf(K[d], aa.w + bb.w, m3);
        }
        const float* xrow = xb + (size_t)h * 1536;
        const int gcb = fc0 + c4;
        float x0v = ((unsigned)(gcb + 0) < 1536u) ? xrow[gcb + 0] : 0.0f;
        float x1v = ((unsigned)(gcb + 1) < 1536u) ? xrow[gcb + 1] : 0.0f;
        float x2v = ((unsigned)(gcb + 2) < 1536u) ? xrow[gcb + 2] : 0.0f;
        float x3v = ((unsigned)(gcb + 3) < 1536u) ? xrow[gcb + 3] : 0.0f;
        // out-of-image cols must be exact 0 (zero-pad of second conv)
        float c0 = ((unsigned)(gcb + 0) < 1536u) ? (x0v - m0) : 0.0f;
        float c1 = ((unsigned)(gcb + 1) < 1536u) ? (x1v - m1) : 0.0f;
        float c2 = ((unsigned)(gcb + 2) < 1536u) ? (x2v - m2) : 0.0f;
        float c3 = ((unsigned)(gcb + 3) < 1536u) ? (x3v - m3) : 0.0f;
        *dst = make_float4(c0, c1, c2, c3);
    }
    __syncthreads();

    // ---------------- Phase 3: hblur(b2^2) -> hc (reuse s1) -----------------
    float* hc = s1;                        // 26 x 100 (2600 floats <= 4752)
    for (int t = tid; t < B2R * 12; t += 256) {
        const int r   = t / 12;
        const int run = t - r * 12;
        const int tc0 = run * 8;           // tile flat col of first output
        float w[40];                       // b2 idx [tc0, tc0+40)
        const float4* p = (const float4*)&b2[r * S1W + tc0];
        #pragma unroll
        for (int q = 0; q < 10; ++q) {
            float4 v = p[q];
            w[4*q+0] = v.x * v.x; w[4*q+1] = v.y * v.y;
            w[4*q+2] = v.z * v.z; w[4*q+3] = v.w * v.w;
        }
        float v1[8];
        #pragma unroll
        for (int i = 0; i < 8; ++i) {
            const int ci = 15 + i;         // center: b2 idx = tc0+i+15
            float acc = K[0] * w[ci];
            #pragma unroll
            for (int d = 1; d <= 5; ++d)
                acc = fmaf(K[d], w[ci - 3*d] + w[ci + 3*d], acc);
            v1[i] = acc;
        }
        float4* dst = (float4*)&hc[r * HCW + tc0];
        dst[0] = make_float4(v1[0], v1[1], v1[2], v1[3]);
        dst[1] = make_float4(v1[4], v1[5], v1[6], v1[7]);
    }
    __syncthreads();

    // ---------------- Phase 4: vblur(hc)=var; epilogue ----------------------
    // task -> (row r of 16, float4-group g4 of 24)
    for (int t = tid; t < TH * 24; t += 256) {
        const int r  = t / 24;
        const int tc = (t - r * 24) * 4;
        float4 v = *(const float4*)&hc[(r + 5) * HCW + tc];
        float s0 = K[0] * v.x, s1v = K[0] * v.y, s2v = K[0] * v.z, s3 = K[0] * v.w;
        #pragma unroll
        for (int d = 1; d <= 5; ++d) {
            float4 aa = *(const float4*)&hc[(r + 5 - d) * HCW + tc];
            float4 bb = *(const float4*)&hc[(r + 5 + d) * HCW + tc];
            s0  = fmaf(K[d], aa.x + bb.x, s0);
            s1v = fmaf(K[d], aa.y + bb.y, s1v);
            s2v = fmaf(K[d], aa.z + bb.z, s2v);
            s3  = fmaf(K[d], aa.w + bb.w, s3);
        }
        const int h = h0 + r;
        const size_t rowoff = (size_t)(bi * 512 + h);
        // centered from b2 (row r+5, col idx tc+15+j) -- misaligned, b32 reads
        const float* bp = &b2[(r + 5) * S1W + tc + 15];
        float c0 = bp[0], c1 = bp[1], c2 = bp[2], c3 = bp[3];
        const float* mrow = mask + rowoff * 512 + w0;
        float mv0 = mrow[(tc + 0) / 3];
        float mv1 = mrow[(tc + 1) / 3];
        float mv2 = mrow[(tc + 2) / 3];
        float mv3 = mrow[(tc + 3) / 3];
        float4 o;
        o.x = c0 * __builtin_amdgcn_rcpf(sqrtf(s0)  + 1e-4f) * mv0;
        o.y = c1 * __builtin_amdgcn_rcpf(sqrtf(s1v) + 1e-4f) * mv1;
        o.z = c2 * __builtin_amdgcn_rcpf(sqrtf(s2v) + 1e-4f) * mv2;
        o.w = c3 * __builtin_amdgcn_rcpf(sqrtf(s3)  + 1e-4f) * mv3;
        *(float4*)&out[rowoff * 1536 + 3 * w0 + tc] = o;
    }
}

extern "C" void kernel_launch(void* const* d_in, const int* in_sizes, int n_in,
                              void* d_out, int out_size, void* d_ws, size_t ws_size,
                              hipStream_t stream) {
    const float* x0   = (const float*)d_in[0];
    const float* mask = (const float*)d_in[1];
    float* out = (float*)d_out;

    dim3 grid(512 / TW, 512 / TH, 32);   // (16, 32, 32) = 16384 blocks
    dim3 block(256);
    lecun_lcn_kernel<<<grid, block, 0, stream>>>(x0, mask, out);
}

// Round 4
// 322.332 us; speedup vs baseline: 1.2503x; 1.2503x over previous
//
#include <hip/hip_runtime.h>
#include <math.h>

// LeCun LCN, fused single kernel, radius-5 truncated Gaussian (taps d>=6 have
// total weight 1.2e-8 -- numerically invisible vs the 4.9e-2 threshold).
//
// mean     = gauss11x11 * x          (separable, zero-pad SAME)
// centered = x - mean
// var      = gauss11x11 * centered^2 (zero-pad SAME)
// out      = centered / (sqrt(var) + 1e-4) * mask
//
// Tile 32x32 (96 flat cols), 256 threads, LDS 49.6 KB -> 3 blocks/CU.
// R1 lesson: TH=16 (5 blocks/CU) LOST 14% -- halo redundancy beats occupancy.
// This round attacks LDS-read volume + dependency chains instead:
//  - vertical phases use SLIDING REGISTER WINDOWS: thread computes a run of
//    rows, reading (run+10) rows once instead of 11 per row
//    (P2: 58 -> 16 ds_read_b128/thread, P4: 33 -> 14)
//  - horizontal phases use runs of 16 (12 dwordx4 per 16 outputs vs 10 per 8)
//  - P4 centered read: 2 aligned ds_read_b128 instead of 4 misaligned b32
//    (those were 6-way bank conflicts)
//
//  P1: hblur(x)        -> s1[52][132]  rows h0-10..h0+41, flat cols fc0..fc0+125
//  P2: vblur(s1)=mean; centered -> b2[42][132]  rows h0-5..h0+36
//  P3: hblur(b2^2)     -> hc (reuse s1) [42][104]
//  P4: vblur(hc)=var; epilogue, float4 stores

#define TW 32
#define TH 32
#define S1W 132          // LDS row stride (126 cols used + pad)
#define S1R 52           // TH + 20
#define B2R 42           // TH + 10
#define HCW 104          // hc row stride (416 B == 32 mod 128 -> row rotation)

__global__ __launch_bounds__(256, 3)
void lecun_lcn_kernel(const float* __restrict__ x,
                      const float* __restrict__ mask,
                      float* __restrict__ out)
{
    __shared__ float s1[S1R * S1W];   // 27,456 B
    __shared__ float b2[B2R * S1W];   // 22,176 B   (total 49,632 -> 3 blocks/CU)

    const int tid = threadIdx.x;
    const int w0  = blockIdx.x * TW;
    const int h0  = blockIdx.y * TH;
    const int bi  = blockIdx.z;
    const int fc0 = 3 * w0 - 15;      // flat col of s1/b2 index 0

    // 1D Gaussian (std=1), taps 0..5, normalized by the full 19-tap sum.
    const float K[6] = {
        3.9894227826685783e-01f,
        2.4197072322439816e-01f,
        5.3990966224238430e-02f,
        4.4318483882270000e-03f,
        1.3383022504889000e-04f,
        1.4867195067806000e-06f
    };

    const float* xb = x + (size_t)bi * 512 * 1536;

    // ---------------- Phase 1: hblur(x) -> s1 -------------------------------
    // task -> (row r of 52, run of 16 cols; 8 runs cover 128 cols)
    for (int t = tid; t < S1R * 8; t += 256) {
        const int r   = t >> 3;
        const int run = t & 7;
        const int h   = h0 - 10 + r;
        float* dst = &s1[r * S1W + run * 16];
        if ((unsigned)h >= 512u) {
            float4 z = make_float4(0.f, 0.f, 0.f, 0.f);
            ((float4*)dst)[0] = z; ((float4*)dst)[1] = z;
            ((float4*)dst)[2] = z; ((float4*)dst)[3] = z;
            continue;
        }
        const float* xrow = xb + (size_t)h * 1536;
        const int gc0 = fc0 + run * 16;    // first output flat col
        const int a   = gc0 - 17;          // window start; gc0%4==1 -> a%4==0
        float w[48];                       // x[a .. a+47]; taps use w[2..47]
        if (a >= 0 && a <= 1536 - 48) {
            const float4* p = (const float4*)(xrow + a);
            #pragma unroll
            for (int q = 0; q < 12; ++q) {
                float4 v = p[q];
                w[4*q+0] = v.x; w[4*q+1] = v.y; w[4*q+2] = v.z; w[4*q+3] = v.w;
            }
        } else {
            #pragma unroll
            for (int i = 0; i < 48; ++i) {
                int j = a + i;
                w[i] = ((unsigned)j < 1536u) ? xrow[j] : 0.0f;
            }
        }
        float v1[16];
        #pragma unroll
        for (int i = 0; i < 16; ++i) {
            const int ci = 17 + i;         // center x[gc0+i] at w[17+i]
            float acc = K[0] * w[ci];
            #pragma unroll
            for (int d = 1; d <= 5; ++d)
                acc = fmaf(K[d], w[ci - 3*d] + w[ci + 3*d], acc);
            v1[i] = acc;
        }
        ((float4*)dst)[0] = make_float4(v1[0],  v1[1],  v1[2],  v1[3]);
        ((float4*)dst)[1] = make_float4(v1[4],  v1[5],  v1[6],  v1[7]);
        ((float4*)dst)[2] = make_float4(v1[8],  v1[9],  v1[10], v1[11]);
        ((float4*)dst)[3] = make_float4(v1[12], v1[13], v1[14], v1[15]);
    }
    __syncthreads();

    // ------- Phase 2: vblur(s1)=mean; centered = x - mean -> b2 -------------
    // Sliding window: thread (quad, rt) owns col-quad and a run of 5-6 rows.
    // rt<6 -> rows 5*rt..5*rt+4; rt=6 -> 30..35; rt=7 -> 36..41 (42 total).
    // cnt is uniform per wave (wave w holds rt=2w,2w+1).
    {
        const int quad = tid & 31;
        const int rt   = tid >> 5;
        const int cnt  = (rt < 6) ? 5 : 6;
        const int rb   = (rt < 6) ? 5 * rt : 30 + 6 * (rt - 6);
        const int c4   = quad * 4;
        float4 w[16];                      // s1 rows rb..rb+cnt+9
        #pragma unroll
        for (int k = 0; k < 16; ++k) {
            if (k < cnt + 10)
                w[k] = *(const float4*)&s1[(rb + k) * S1W + c4];
        }
        #pragma unroll
        for (int j = 0; j < 6; ++j) {
            if (j < cnt) {
                const int r = rb + j;
                const int h = h0 - 5 + r;
                float4* dst = (float4*)&b2[r * S1W + c4];
                if ((unsigned)h >= 512u) {
                    *dst = make_float4(0.f, 0.f, 0.f, 0.f);
                } else {
                    float m0 = K[0] * w[j+5].x, m1 = K[0] * w[j+5].y;
                    float m2 = K[0] * w[j+5].z, m3 = K[0] * w[j+5].w;
                    #pragma unroll
                    for (int d = 1; d <= 5; ++d) {
                        float4 aa = w[j + 5 - d];
                        float4 bb = w[j + 5 + d];
                        m0 = fmaf(K[d], aa.x + bb.x, m0);
                        m1 = fmaf(K[d], aa.y + bb.y, m1);
                        m2 = fmaf(K[d], aa.z + bb.z, m2);
                        m3 = fmaf(K[d], aa.w + bb.w, m3);
                    }
                    const float* xrow = xb + (size_t)h * 1536;
                    const int gcb = fc0 + c4;
                    float x0v = ((unsigned)(gcb + 0) < 1536u) ? xrow[gcb + 0] : 0.0f;
                    float x1v = ((unsigned)(gcb + 1) < 1536u) ? xrow[gcb + 1] : 0.0f;
                    float x2v = ((unsigned)(gcb + 2) < 1536u) ? xrow[gcb + 2] : 0.0f;
                    float x3v = ((unsigned)(gcb + 3) < 1536u) ? xrow[gcb + 3] : 0.0f;
                    // out-of-image cols must be exact 0 (zero-pad of second conv)
                    float c0 = ((unsigned)(gcb + 0) < 1536u) ? (x0v - m0) : 0.0f;
                    float c1 = ((unsigned)(gcb + 1) < 1536u) ? (x1v - m1) : 0.0f;
                    float c2 = ((unsigned)(gcb + 2) < 1536u) ? (x2v - m2) : 0.0f;
                    float c3 = ((unsigned)(gcb + 3) < 1536u) ? (x3v - m3) : 0.0f;
                    *dst = make_float4(c0, c1, c2, c3);
                }
            }
        }
    }
    __syncthreads();

    // ---------------- Phase 3: hblur(b2^2) -> hc (reuse s1) -----------------
    // task -> (row r of 42, run of 16; 6 runs cover 96 cols). 252 tasks.
    float* hc = s1;                        // 42 x 104 = 4368 floats <= 6864
    for (int t = tid; t < B2R * 6; t += 256) {
        const int r   = t / 6;
        const int run = t - r * 6;
        const int tc0 = run * 16;          // tile col of first output
        float w[48];                       // b2 idx [tc0, tc0+48): squares
        const float4* p = (const float4*)&b2[r * S1W + tc0];
        #pragma unroll
        for (int q = 0; q < 12; ++q) {
            float4 v = p[q];
            w[4*q+0] = v.x * v.x; w[4*q+1] = v.y * v.y;
            w[4*q+2] = v.z * v.z; w[4*q+3] = v.w * v.w;
        }
        float v1[16];
        #pragma unroll
        for (int i = 0; i < 16; ++i) {
            const int ci = 15 + i;         // center: b2 idx = tc0+i+15
            float acc = K[0] * w[ci];
            #pragma unroll
            for (int d = 1; d <= 5; ++d)
                acc = fmaf(K[d], w[ci - 3*d] + w[ci + 3*d], acc);
            v1[i] = acc;
        }
        float4* dst = (float4*)&hc[r * HCW + tc0];
        dst[0] = make_float4(v1[0],  v1[1],  v1[2],  v1[3]);
        dst[1] = make_float4(v1[4],  v1[5],  v1[6],  v1[7]);
        dst[2] = make_float4(v1[8],  v1[9],  v1[10], v1[11]);
        dst[3] = make_float4(v1[12], v1[13], v1[14], v1[15]);
    }
    __syncthreads();

    // ---------------- Phase 4: vblur(hc)=var; epilogue ----------------------
    // Sliding window: thread (quad<24, rt) owns col-quad tc=4*quad and rows
    // 4*rt..4*rt+3. Window = 14 rows of hc in registers.
    {
        const int quad = tid & 31;
        const int rt   = tid >> 5;
        if (quad < 24) {
            const int tc = quad * 4;
            const int r0 = rt * 4;
            float4 w[14];                  // hc rows r0..r0+13
            #pragma unroll
            for (int k = 0; k < 14; ++k)
                w[k] = *(const float4*)&hc[(r0 + k) * HCW + tc];
            #pragma unroll
            for (int j = 0; j < 4; ++j) {
                float s0 = K[0] * w[j+5].x, s1v = K[0] * w[j+5].y;
                float s2v = K[0] * w[j+5].z, s3 = K[0] * w[j+5].w;
                #pragma unroll
                for (int d = 1; d <= 5; ++d) {
                    float4 aa = w[j + 5 - d];
                    float4 bb = w[j + 5 + d];
                    s0  = fmaf(K[d], aa.x + bb.x, s0);
                    s1v = fmaf(K[d], aa.y + bb.y, s1v);
                    s2v = fmaf(K[d], aa.z + bb.z, s2v);
                    s3  = fmaf(K[d], aa.w + bb.w, s3);
                }
                const int r = r0 + j;
                const int h = h0 + r;
                const size_t rowoff = (size_t)(bi * 512 + h);
                // centered from b2 row r+5, cols tc+15..tc+18:
                // two ALIGNED b128 reads (was 4 misaligned b32 = 6-way conflict)
                float4 A = *(const float4*)&b2[(r + 5) * S1W + tc + 12];
                float4 B = *(const float4*)&b2[(r + 5) * S1W + tc + 16];
                float c0 = A.w, c1 = B.x, c2 = B.y, c3 = B.z;
                const float* mrow = mask + rowoff * 512 + w0;
                float mv0 = mrow[(tc + 0) / 3];
                float mv1 = mrow[(tc + 1) / 3];
                float mv2 = mrow[(tc + 2) / 3];
                float mv3 = mrow[(tc + 3) / 3];
                float4 o;
                o.x = c0 * __builtin_amdgcn_rcpf(sqrtf(s0)  + 1e-4f) * mv0;
                o.y = c1 * __builtin_amdgcn_rcpf(sqrtf(s1v) + 1e-4f) * mv1;
                o.z = c2 * __builtin_amdgcn_rcpf(sqrtf(s2v) + 1e-4f) * mv2;
                o.w = c3 * __builtin_amdgcn_rcpf(sqrtf(s3)  + 1e-4f) * mv3;
                *(float4*)&out[rowoff * 1536 + 3 * w0 + tc] = o;
            }
        }
    }
}

extern "C" void kernel_launch(void* const* d_in, const int* in_sizes, int n_in,
                              void* d_out, int out_size, void* d_ws, size_t ws_size,
                              hipStream_t stream) {
    const float* x0   = (const float*)d_in[0];
    const float* mask = (const float*)d_in[1];
    float* out = (float*)d_out;

    dim3 grid(512 / TW, 512 / TH, 32);   // (16, 16, 32) = 8192 blocks
    dim3 block(256);
    lecun_lcn_kernel<<<grid, block, 0, stream>>>(x0, mask, out);
}

// Round 7
// 309.306 us; speedup vs baseline: 1.3030x; 1.0421x over previous
//
#include <hip/hip_runtime.h>
#include <math.h>

// LeCun LCN, fused single kernel, radius-5 truncated Gaussian (taps d>=6 have
// total weight 1.2e-8 -- numerically invisible vs the 4.9e-2 threshold).
//
// mean     = gauss11x11 * x          (separable, zero-pad SAME)
// centered = x - mean
// var      = gauss11x11 * centered^2 (zero-pad SAME)
// out      = centered / (sqrt(var) + 1e-4) * mask
//
// Tile 32x32 (96 flat cols), 256 threads, LDS 49.6 KB -> 3 blocks/CU.
// R1 lesson: TH=16 (5 blocks/CU) LOST 14% -- halo redundancy beats occupancy.
// R4 lesson: sliding register windows in vertical phases = -21% (245->194us).
// R5: conv-2 order SWAPPED to vblur-then-hblur. Same op count (7104 conv
// outputs either way) but kills old-P4's ~6-way bank-conflict column-window
// reads (48 lanes x 16B over a 384B row-span, rt-groups 4 rows apart with
// 4*HCW==0 mod 32 -> same banks). New P4' reads are row-major spread.
//
//  P1: hblur(x)         -> s1[52][132]  rows h0-10..h0+41, cols fc0..fc0+125
//  P2: vblur(s1)=mean; centered=x-mean -> b2[42][132]  rows h0-5..h0+36
//  P3': vblur(b2^2)     -> vc (reuse s1) [32][132], output rows h0..h0+31
//  P4': hblur(vc)=var; epilogue, 256 tasks (row, 12-col run), float4 stores

#define TW 32
#define TH 32
#define S1W 132          // LDS row stride (126 cols used + pad; 132%32=4)
#define S1R 52           // TH + 20
#define B2R 42           // TH + 10

__global__ __launch_bounds__(256, 3)
void lecun_lcn_kernel(const float* __restrict__ x,
                      const float* __restrict__ mask,
                      float* __restrict__ out)
{
    __shared__ float s1[S1R * S1W];   // 27,456 B
    __shared__ float b2[B2R * S1W];   // 22,176 B   (total 49,632 -> 3 blocks/CU)

    const int tid = threadIdx.x;
    const int w0  = blockIdx.x * TW;
    const int h0  = blockIdx.y * TH;
    const int bi  = blockIdx.z;
    const int fc0 = 3 * w0 - 15;      // flat col of s1/b2/vc index 0

    // 1D Gaussian (std=1), taps 0..5, normalized by the full 19-tap sum.
    const float K[6] = {
        3.9894227826685783e-01f,
        2.4197072322439816e-01f,
        5.3990966224238430e-02f,
        4.4318483882270000e-03f,
        1.3383022504889000e-04f,
        1.4867195067806000e-06f
    };

    const float* xb = x + (size_t)bi * 512 * 1536;

    // ---------------- Phase 1: hblur(x) -> s1 -------------------------------
    // task -> (row r of 52, run of 16 cols; 8 runs cover 128 cols)
    for (int t = tid; t < S1R * 8; t += 256) {
        const int r   = t >> 3;
        const int run = t & 7;
        const int h   = h0 - 10 + r;
        float* dst = &s1[r * S1W + run * 16];
        if ((unsigned)h >= 512u) {
            float4 z = make_float4(0.f, 0.f, 0.f, 0.f);
            ((float4*)dst)[0] = z; ((float4*)dst)[1] = z;
            ((float4*)dst)[2] = z; ((float4*)dst)[3] = z;
            continue;
        }
        const float* xrow = xb + (size_t)h * 1536;
        const int gc0 = fc0 + run * 16;    // first output flat col
        const int a   = gc0 - 17;          // window start; gc0%4==1 -> a%4==0
        float w[48];                       // x[a .. a+47]; taps use w[2..47]
        if (a >= 0 && a <= 1536 - 48) {
            const float4* p = (const float4*)(xrow + a);
            #pragma unroll
            for (int q = 0; q < 12; ++q) {
                float4 v = p[q];
                w[4*q+0] = v.x; w[4*q+1] = v.y; w[4*q+2] = v.z; w[4*q+3] = v.w;
            }
        } else {
            #pragma unroll
            for (int i = 0; i < 48; ++i) {
                int j = a + i;
                w[i] = ((unsigned)j < 1536u) ? xrow[j] : 0.0f;
            }
        }
        float v1[16];
        #pragma unroll
        for (int i = 0; i < 16; ++i) {
            const int ci = 17 + i;         // center x[gc0+i] at w[17+i]
            float acc = K[0] * w[ci];
            #pragma unroll
            for (int d = 1; d <= 5; ++d)
                acc = fmaf(K[d], w[ci - 3*d] + w[ci + 3*d], acc);
            v1[i] = acc;
        }
        ((float4*)dst)[0] = make_float4(v1[0],  v1[1],  v1[2],  v1[3]);
        ((float4*)dst)[1] = make_float4(v1[4],  v1[5],  v1[6],  v1[7]);
        ((float4*)dst)[2] = make_float4(v1[8],  v1[9],  v1[10], v1[11]);
        ((float4*)dst)[3] = make_float4(v1[12], v1[13], v1[14], v1[15]);
    }
    __syncthreads();

    // ------- Phase 2: vblur(s1)=mean; centered = x - mean -> b2 -------------
    // Sliding window: thread (quad, rt) owns col-quad and a run of 5-6 rows.
    // rt<6 -> rows 5*rt..5*rt+4; rt=6 -> 30..35; rt=7 -> 36..41 (42 total).
    // cnt is uniform per wave (wave w holds rt=2w,2w+1).
    {
        const int quad = tid & 31;
        const int rt   = tid >> 5;
        const int cnt  = (rt < 6) ? 5 : 6;
        const int rb   = (rt < 6) ? 5 * rt : 30 + 6 * (rt - 6);
        const int c4   = quad * 4;
        const int gcb  = fc0 + c4;
        // col validity is row-invariant: hoist out of the j loop
        const bool cv0 = (unsigned)(gcb + 0) < 1536u;
        const bool cv1 = (unsigned)(gcb + 1) < 1536u;
        const bool cv2 = (unsigned)(gcb + 2) < 1536u;
        const bool cv3 = (unsigned)(gcb + 3) < 1536u;
        float4 w[16];                      // s1 rows rb..rb+cnt+9
        #pragma unroll
        for (int k = 0; k < 16; ++k) {
            if (k < cnt + 10)
                w[k] = *(const float4*)&s1[(rb + k) * S1W + c4];
        }
        #pragma unroll
        for (int j = 0; j < 6; ++j) {
            if (j < cnt) {
                const int r = rb + j;
                const int h = h0 - 5 + r;
                float4* dst = (float4*)&b2[r * S1W + c4];
                if ((unsigned)h >= 512u) {
                    *dst = make_float4(0.f, 0.f, 0.f, 0.f);
                } else {
                    float m0 = K[0] * w[j+5].x, m1 = K[0] * w[j+5].y;
                    float m2 = K[0] * w[j+5].z, m3 = K[0] * w[j+5].w;
                    #pragma unroll
                    for (int d = 1; d <= 5; ++d) {
                        float4 aa = w[j + 5 - d];
                        float4 bb = w[j + 5 + d];
                        m0 = fmaf(K[d], aa.x + bb.x, m0);
                        m1 = fmaf(K[d], aa.y + bb.y, m1);
                        m2 = fmaf(K[d], aa.z + bb.z, m2);
                        m3 = fmaf(K[d], aa.w + bb.w, m3);
                    }
                    const float* xrow = xb + (size_t)h * 1536;
                    // out-of-image cols must be exact 0 (zero-pad of second conv)
                    float c0 = cv0 ? (xrow[gcb + 0] - m0) : 0.0f;
                    float c1 = cv1 ? (xrow[gcb + 1] - m1) : 0.0f;
                    float c2 = cv2 ? (xrow[gcb + 2] - m2) : 0.0f;
                    float c3 = cv3 ? (xrow[gcb + 3] - m3) : 0.0f;
                    *dst = make_float4(c0, c1, c2, c3);
                }
            }
        }
    }
    __syncthreads();

    // ---------------- Phase 3': vblur(b2^2) -> vc (reuse s1) ----------------
    // Sliding window like P2: thread (quad, rt) owns col-quad c4 and output
    // rows 4*rt..4*rt+3 (h0-relative). Window = b2 rows 4rt..4rt+13, squared
    // on the fly. vc[r][c], r=0..31, c=0..127, stride S1W.
    float* vc = s1;                        // 32 x 132 = 4224 floats <= 6864
    {
        const int quad = tid & 31;
        const int rt   = tid >> 5;
        const int r0   = rt * 4;
        const int c4   = quad * 4;
        float4 w[14];                      // b2sq rows r0..r0+13
        #pragma unroll
        for (int k = 0; k < 14; ++k) {
            float4 v = *(const float4*)&b2[(r0 + k) * S1W + c4];
            w[k] = make_float4(v.x*v.x, v.y*v.y, v.z*v.z, v.w*v.w);
        }
        #pragma unroll
        for (int j = 0; j < 4; ++j) {
            float s0 = K[0] * w[j+5].x, s1v = K[0] * w[j+5].y;
            float s2v = K[0] * w[j+5].z, s3 = K[0] * w[j+5].w;
            #pragma unroll
            for (int d = 1; d <= 5; ++d) {
                float4 aa = w[j + 5 - d];
                float4 bb = w[j + 5 + d];
                s0  = fmaf(K[d], aa.x + bb.x, s0);
                s1v = fmaf(K[d], aa.y + bb.y, s1v);
                s2v = fmaf(K[d], aa.z + bb.z, s2v);
                s3  = fmaf(K[d], aa.w + bb.w, s3);
            }
            *(float4*)&vc[(r0 + j) * S1W + c4] = make_float4(s0, s1v, s2v, s3);
        }
    }
    __syncthreads();

    // ---------------- Phase 4': hblur(vc)=var; epilogue ---------------------
    // 256 tasks: (row r = t>>3, run = t&7), 12 flat cols per task.
    // Output flat col = 3*w0 + 12*run + j, j=0..11; vc idx = 15 + 12*run + j.
    // Window: vc idx [12run, 12run+41] -> 11 aligned b128. Row-major spread:
    // a wave's 64 lanes cover 8 rows x 8 runs -> no column-window conflicts.
    {
        const int r    = tid >> 3;
        const int run  = tid & 7;
        const int tc0  = run * 12;
        float w[44];                       // vc[r][tc0 .. tc0+43]
        #pragma unroll
        for (int q = 0; q < 11; ++q) {
            float4 v = *(const float4*)&vc[r * S1W + tc0 + 4*q];
            w[4*q+0] = v.x; w[4*q+1] = v.y; w[4*q+2] = v.z; w[4*q+3] = v.w;
        }
        // centered at vc idx 15+12run+j -> b2 row r+5, rel floats 15..26:
        // 4 aligned b128 covering rel 12..27
        float cw[16];
        #pragma unroll
        for (int q = 0; q < 4; ++q) {
            float4 v = *(const float4*)&b2[(r + 5) * S1W + tc0 + 12 + 4*q];
            cw[4*q+0] = v.x; cw[4*q+1] = v.y; cw[4*q+2] = v.z; cw[4*q+3] = v.w;
        }
        const int h = h0 + r;
        const size_t rowoff = (size_t)(bi * 512 + h);
        const float* mrow = mask + rowoff * 512 + w0 + 4 * run;
        float mv[4];
        #pragma unroll
        for (int k = 0; k < 4; ++k) mv[k] = mrow[k];
        float o[12];
        #pragma unroll
        for (int j = 0; j < 12; ++j) {
            const int ci = 15 + j;         // center in w
            float var = K[0] * w[ci];
            #pragma unroll
            for (int d = 1; d <= 5; ++d)
                var = fmaf(K[d], w[ci - 3*d] + w[ci + 3*d], var);
            o[j] = cw[j + 3] * __builtin_amdgcn_rcpf(sqrtf(var) + 1e-4f) * mv[j / 3];
        }
        float* orow = &out[rowoff * 1536 + 3 * w0 + tc0];
        ((float4*)orow)[0] = make_float4(o[0], o[1], o[2],  o[3]);
        ((float4*)orow)[1] = make_float4(o[4], o[5], o[6],  o[7]);
        ((float4*)orow)[2] = make_float4(o[8], o[9], o[10], o[11]);
    }
}

extern "C" void kernel_launch(void* const* d_in, const int* in_sizes, int n_in,
                              void* d_out, int out_size, void* d_ws, size_t ws_size,
                              hipStream_t stream) {
    const float* x0   = (const float*)d_in[0];
    const float* mask = (const float*)d_in[1];
    float* out = (float*)d_out;

    dim3 grid(512 / TW, 512 / TH, 32);   // (16, 16, 32) = 8192 blocks
    dim3 block(256);
    lecun_lcn_kernel<<<grid, block, 0, stream>>>(x0, mask, out);
}

// Round 8
// 306.961 us; speedup vs baseline: 1.3129x; 1.0076x over previous
//
#include <hip/hip_runtime.h>
#include <math.h>

// LeCun LCN, fused single kernel, radius-5 truncated Gaussian (taps d>=6 have
// total weight 1.2e-8 -- numerically invisible vs the 4.9e-2 threshold).
//
// mean     = gauss11x11 * x          (separable, zero-pad SAME)
// centered = x - mean
// var      = gauss11x11 * centered^2 (zero-pad SAME)
// out      = centered / (sqrt(var) + 1e-4) * mask
//
// Tile 32x32 (96 flat cols), 256 threads.
// R1 lesson: TH=16 (5 blocks/CU) LOST 14% -- it bought occupancy with +25%
//            halo work.
// R4 lesson: sliding register windows in vertical phases = -21% (245->194us).
// R7 lesson: conv-2 swapped to vblur->hblur = -6% (194->182us), conflicts
//            1.54e7 -> 1.02e7. Still latency-bound: VALU 36%, LDS ~25%,
//            HBM 14%, occupancy 26%.
// R8: occupancy WITHOUT extra work. s1 becomes a 32-row RING (slot = row&31):
//     P1a (s1 rows 0..31) | P2a (b2 rows 0..21) | P1b (s1 rows 32..51 ->
//     slots 0..19) | P2b (b2 rows 22..41, ring-indexed). Same arithmetic,
//     2 extra barriers, LDS 49.6KB -> 39.1KB -> 4 blocks/CU (16 waves).
//
//  s1h ring [32][132]: hblur(x), rows h0-10..h0+41 streamed through
//  b2       [42][132]: centered = x - vblur(s1)
//  vc  (reuse s1h) [32][132]: vblur(b2^2)
//  P4': hblur(vc)=var; epilogue, 256 tasks (row, 12-col run), float4 stores

#define TW 32
#define TH 32
#define S1W 132          // LDS row stride (126 cols used + pad)
#define RING 32          // s1 ring rows (power of 2: slot = row & 31)
#define B2R 42           // TH + 10

__global__ __launch_bounds__(256, 4)
void lecun_lcn_kernel(const float* __restrict__ x,
                      const float* __restrict__ mask,
                      float* __restrict__ out)
{
    __shared__ float s1h[RING * S1W];  // 16,896 B
    __shared__ float b2[B2R * S1W];    // 22,176 B   (total 39,072 -> 4 blocks/CU)

    const int tid = threadIdx.x;
    const int w0  = blockIdx.x * TW;
    const int h0  = blockIdx.y * TH;
    const int bi  = blockIdx.z;
    const int fc0 = 3 * w0 - 15;      // flat col of s1/b2/vc index 0

    // 1D Gaussian (std=1), taps 0..5, normalized by the full 19-tap sum.
    const float K[6] = {
        3.9894227826685783e-01f,
        2.4197072322439816e-01f,
        5.3990966224238430e-02f,
        4.4318483882270000e-03f,
        1.3383022504889000e-04f,
        1.4867195067806000e-06f
    };

    const float* xb = x + (size_t)bi * 512 * 1536;

    // ---------------- Phase 1a: hblur(x) rows 0..31 -> s1h slots 0..31 ------
    // one task per thread: (row r = tid>>3, run of 16 cols; 8 runs = 128 cols)
    {
        const int r   = tid >> 3;          // 0..31  (s1 row r, image h0-10+r)
        const int run = tid & 7;
        const int h   = h0 - 10 + r;
        float* dst = &s1h[r * S1W + run * 16];
        if ((unsigned)h >= 512u) {
            float4 z = make_float4(0.f, 0.f, 0.f, 0.f);
            ((float4*)dst)[0] = z; ((float4*)dst)[1] = z;
            ((float4*)dst)[2] = z; ((float4*)dst)[3] = z;
        } else {
            const float* xrow = xb + (size_t)h * 1536;
            const int gc0 = fc0 + run * 16;    // first output flat col
            const int a   = gc0 - 17;          // window start; a%4==0
            float w[48];
            if (a >= 0 && a <= 1536 - 48) {
                const float4* p = (const float4*)(xrow + a);
                #pragma unroll
                for (int q = 0; q < 12; ++q) {
                    float4 v = p[q];
                    w[4*q+0] = v.x; w[4*q+1] = v.y; w[4*q+2] = v.z; w[4*q+3] = v.w;
                }
            } else {
                #pragma unroll
                for (int i = 0; i < 48; ++i) {
                    int j = a + i;
                    w[i] = ((unsigned)j < 1536u) ? xrow[j] : 0.0f;
                }
            }
            float v1[16];
            #pragma unroll
            for (int i = 0; i < 16; ++i) {
                const int ci = 17 + i;
                float acc = K[0] * w[ci];
                #pragma unroll
                for (int d = 1; d <= 5; ++d)
                    acc = fmaf(K[d], w[ci - 3*d] + w[ci + 3*d], acc);
                v1[i] = acc;
            }
            ((float4*)dst)[0] = make_float4(v1[0],  v1[1],  v1[2],  v1[3]);
            ((float4*)dst)[1] = make_float4(v1[4],  v1[5],  v1[6],  v1[7]);
            ((float4*)dst)[2] = make_float4(v1[8],  v1[9],  v1[10], v1[11]);
            ((float4*)dst)[3] = make_float4(v1[12], v1[13], v1[14], v1[15]);
        }
    }
    __syncthreads();

    // ------- Phase 2a: vblur -> b2 rows 0..21; centered = x - mean ----------
    // thread (quad, rt): rt<6 -> 3 rows at 3rt; rt=6 -> 18,19; rt=7 -> 20,21.
    // cnt uniform per wave (wave w holds rt=2w,2w+1).
    {
        const int quad = tid & 31;
        const int rt   = tid >> 5;
        const int cnt  = (rt < 6) ? 3 : 2;
        const int rb   = (rt < 6) ? 3 * rt : 18 + 2 * (rt - 6);
        const int c4   = quad * 4;
        const int gcb  = fc0 + c4;
        const bool cv0 = (unsigned)(gcb + 0) < 1536u;
        const bool cv1 = (unsigned)(gcb + 1) < 1536u;
        const bool cv2 = (unsigned)(gcb + 2) < 1536u;
        const bool cv3 = (unsigned)(gcb + 3) < 1536u;
        float4 w[13];                      // s1 rows rb..rb+cnt+9 (slots = rows)
        #pragma unroll
        for (int k = 0; k < 13; ++k) {
            if (k < cnt + 10)
                w[k] = *(const float4*)&s1h[(rb + k) * S1W + c4];
        }
        #pragma unroll
        for (int j = 0; j < 3; ++j) {
            if (j < cnt) {
                const int r = rb + j;
                const int h = h0 - 5 + r;
                float4* dst = (float4*)&b2[r * S1W + c4];
                if ((unsigned)h >= 512u) {
                    *dst = make_float4(0.f, 0.f, 0.f, 0.f);
                } else {
                    float m0 = K[0] * w[j+5].x, m1 = K[0] * w[j+5].y;
                    float m2 = K[0] * w[j+5].z, m3 = K[0] * w[j+5].w;
                    #pragma unroll
                    for (int d = 1; d <= 5; ++d) {
                        float4 aa = w[j + 5 - d];
                        float4 bb = w[j + 5 + d];
                        m0 = fmaf(K[d], aa.x + bb.x, m0);
                        m1 = fmaf(K[d], aa.y + bb.y, m1);
                        m2 = fmaf(K[d], aa.z + bb.z, m2);
                        m3 = fmaf(K[d], aa.w + bb.w, m3);
                    }
                    const float* xrow = xb + (size_t)h * 1536;
                    // out-of-image cols must be exact 0 (zero-pad of conv-2)
                    float c0 = cv0 ? (xrow[gcb + 0] - m0) : 0.0f;
                    float c1 = cv1 ? (xrow[gcb + 1] - m1) : 0.0f;
                    float c2 = cv2 ? (xrow[gcb + 2] - m2) : 0.0f;
                    float c3 = cv3 ? (xrow[gcb + 3] - m3) : 0.0f;
                    *dst = make_float4(c0, c1, c2, c3);
                }
            }
        }
    }
    __syncthreads();

    // ---------------- Phase 1b: hblur(x) rows 32..51 -> slots 0..19 ---------
    if (tid < 20 * 8) {
        const int r2  = tid >> 3;          // 0..19  (s1 row 32+r2)
        const int run = tid & 7;
        const int h   = h0 + 22 + r2;      // h0-10+(32+r2)
        float* dst = &s1h[r2 * S1W + run * 16];   // slot (32+r2)&31 = r2
        if ((unsigned)h >= 512u) {
            float4 z = make_float4(0.f, 0.f, 0.f, 0.f);
            ((float4*)dst)[0] = z; ((float4*)dst)[1] = z;
            ((float4*)dst)[2] = z; ((float4*)dst)[3] = z;
        } else {
            const float* xrow = xb + (size_t)h * 1536;
            const int gc0 = fc0 + run * 16;
            const int a   = gc0 - 17;
            float w[48];
            if (a >= 0 && a <= 1536 - 48) {
                const float4* p = (const float4*)(xrow + a);
                #pragma unroll
                for (int q = 0; q < 12; ++q) {
                    float4 v = p[q];
                    w[4*q+0] = v.x; w[4*q+1] = v.y; w[4*q+2] = v.z; w[4*q+3] = v.w;
                }
            } else {
                #pragma unroll
                for (int i = 0; i < 48; ++i) {
                    int j = a + i;
                    w[i] = ((unsigned)j < 1536u) ? xrow[j] : 0.0f;
                }
            }
            float v1[16];
            #pragma unroll
            for (int i = 0; i < 16; ++i) {
                const int ci = 17 + i;
                float acc = K[0] * w[ci];
                #pragma unroll
                for (int d = 1; d <= 5; ++d)
                    acc = fmaf(K[d], w[ci - 3*d] + w[ci + 3*d], acc);
                v1[i] = acc;
            }
            ((float4*)dst)[0] = make_float4(v1[0],  v1[1],  v1[2],  v1[3]);
            ((float4*)dst)[1] = make_float4(v1[4],  v1[5],  v1[6],  v1[7]);
            ((float4*)dst)[2] = make_float4(v1[8],  v1[9],  v1[10], v1[11]);
            ((float4*)dst)[3] = make_float4(v1[12], v1[13], v1[14], v1[15]);
        }
    }
    __syncthreads();

    // ------- Phase 2b: vblur -> b2 rows 22..41 (ring-indexed s1 reads) ------
    // rt<4 -> 3 rows at 22+3rt (22..33); rt>=4 -> 2 rows at 34+2(rt-4).
    // cnt uniform per wave.
    {
        const int quad = tid & 31;
        const int rt   = tid >> 5;
        const int cnt  = (rt < 4) ? 3 : 2;
        const int rb   = (rt < 4) ? 22 + 3 * rt : 34 + 2 * (rt - 4);
        const int c4   = quad * 4;
        const int gcb  = fc0 + c4;
        const bool cv0 = (unsigned)(gcb + 0) < 1536u;
        const bool cv1 = (unsigned)(gcb + 1) < 1536u;
        const bool cv2 = (unsigned)(gcb + 2) < 1536u;
        const bool cv3 = (unsigned)(gcb + 3) < 1536u;
        float4 w[13];                      // s1 rows rb..rb+cnt+9, slot = row&31
        #pragma unroll
        for (int k = 0; k < 13; ++k) {
            if (k < cnt + 10)
                w[k] = *(const float4*)&s1h[((rb + k) & 31) * S1W + c4];
        }
        #pragma unroll
        for (int j = 0; j < 3; ++j) {
            if (j < cnt) {
                const int r = rb + j;
                const int h = h0 - 5 + r;
                float4* dst = (float4*)&b2[r * S1W + c4];
                if ((unsigned)h >= 512u) {
                    *dst = make_float4(0.f, 0.f, 0.f, 0.f);
                } else {
                    float m0 = K[0] * w[j+5].x, m1 = K[0] * w[j+5].y;
                    float m2 = K[0] * w[j+5].z, m3 = K[0] * w[j+5].w;
                    #pragma unroll
                    for (int d = 1; d <= 5; ++d) {
                        float4 aa = w[j + 5 - d];
                        float4 bb = w[j + 5 + d];
                        m0 = fmaf(K[d], aa.x + bb.x, m0);
                        m1 = fmaf(K[d], aa.y + bb.y, m1);
                        m2 = fmaf(K[d], aa.z + bb.z, m2);
                        m3 = fmaf(K[d], aa.w + bb.w, m3);
                    }
                    const float* xrow = xb + (size_t)h * 1536;
                    float c0 = cv0 ? (xrow[gcb + 0] - m0) : 0.0f;
                    float c1 = cv1 ? (xrow[gcb + 1] - m1) : 0.0f;
                    float c2 = cv2 ? (xrow[gcb + 2] - m2) : 0.0f;
                    float c3 = cv3 ? (xrow[gcb + 3] - m3) : 0.0f;
                    *dst = make_float4(c0, c1, c2, c3);
                }
            }
        }
    }
    __syncthreads();

    // ---------------- Phase 3': vblur(b2^2) -> vc (reuse s1h) ---------------
    // thread (quad, rt) owns col-quad c4 and output rows 4rt..4rt+3.
    float* vc = s1h;                       // 32 x 132 fits the ring exactly
    {
        const int quad = tid & 31;
        const int rt   = tid >> 5;
        const int r0   = rt * 4;
        const int c4   = quad * 4;
        float4 w[14];                      // b2sq rows r0..r0+13
        #pragma unroll
        for (int k = 0; k < 14; ++k) {
            float4 v = *(const float4*)&b2[(r0 + k) * S1W + c4];
            w[k] = make_float4(v.x*v.x, v.y*v.y, v.z*v.z, v.w*v.w);
        }
        #pragma unroll
        for (int j = 0; j < 4; ++j) {
            float s0 = K[0] * w[j+5].x, s1v = K[0] * w[j+5].y;
            float s2v = K[0] * w[j+5].z, s3 = K[0] * w[j+5].w;
            #pragma unroll
            for (int d = 1; d <= 5; ++d) {
                float4 aa = w[j + 5 - d];
                float4 bb = w[j + 5 + d];
                s0  = fmaf(K[d], aa.x + bb.x, s0);
                s1v = fmaf(K[d], aa.y + bb.y, s1v);
                s2v = fmaf(K[d], aa.z + bb.z, s2v);
                s3  = fmaf(K[d], aa.w + bb.w, s3);
            }
            *(float4*)&vc[(r0 + j) * S1W + c4] = make_float4(s0, s1v, s2v, s3);
        }
    }
    __syncthreads();

    // ---------------- Phase 4': hblur(vc)=var; epilogue ---------------------
    // 256 tasks: (row r = tid>>3, run = tid&7), 12 flat cols per task.
    {
        const int r    = tid >> 3;
        const int run  = tid & 7;
        const int tc0  = run * 12;
        float w[44];                       // vc[r][tc0 .. tc0+43]
        #pragma unroll
        for (int q = 0; q < 11; ++q) {
            float4 v = *(const float4*)&vc[r * S1W + tc0 + 4*q];
            w[4*q+0] = v.x; w[4*q+1] = v.y; w[4*q+2] = v.z; w[4*q+3] = v.w;
        }
        // centered at b2 row r+5, rel floats 15..26: 4 aligned b128
        float cw[16];
        #pragma unroll
        for (int q = 0; q < 4; ++q) {
            float4 v = *(const float4*)&b2[(r + 5) * S1W + tc0 + 12 + 4*q];
            cw[4*q+0] = v.x; cw[4*q+1] = v.y; cw[4*q+2] = v.z; cw[4*q+3] = v.w;
        }
        const int h = h0 + r;
        const size_t rowoff = (size_t)(bi * 512 + h);
        const float* mrow = mask + rowoff * 512 + w0 + 4 * run;
        float mv[4];
        #pragma unroll
        for (int k = 0; k < 4; ++k) mv[k] = mrow[k];
        float o[12];
        #pragma unroll
        for (int j = 0; j < 12; ++j) {
            const int ci = 15 + j;
            float var = K[0] * w[ci];
            #pragma unroll
            for (int d = 1; d <= 5; ++d)
                var = fmaf(K[d], w[ci - 3*d] + w[ci + 3*d], var);
            o[j] = cw[j + 3] * __builtin_amdgcn_rcpf(sqrtf(var) + 1e-4f) * mv[j / 3];
        }
        float* orow = &out[rowoff * 1536 + 3 * w0 + tc0];
        ((float4*)orow)[0] = make_float4(o[0], o[1], o[2],  o[3]);
        ((float4*)orow)[1] = make_float4(o[4], o[5], o[6],  o[7]);
        ((float4*)orow)[2] = make_float4(o[8], o[9], o[10], o[11]);
    }
}

extern "C" void kernel_launch(void* const* d_in, const int* in_sizes, int n_in,
                              void* d_out, int out_size, void* d_ws, size_t ws_size,
                              hipStream_t stream) {
    const float* x0   = (const float*)d_in[0];
    const float* mask = (const float*)d_in[1];
    float* out = (float*)d_out;

    dim3 grid(512 / TW, 512 / TH, 32);   // (16, 16, 32) = 8192 blocks
    dim3 block(256);
    lecun_lcn_kernel<<<grid, block, 0, stream>>>(x0, mask, out);
}